// Round 1
// baseline (221.684 us; speedup 1.0000x reference)
//
#include <hip/hip_runtime.h>

// Problem constants
#define D 32
#define K 8
#define NPAIR 36          // unordered pairs i<=j; off-diagonals get +ln2 multiplicity
#define MSTRIDE 36        // padded row stride for invLc (bank-conflict-free for 4 roles)

// ws layout (float offsets)
#define MOFF 0                        // invLc full 8 x 32 x 36 (upper + pad zeroed)
#define WOFF (K*D*MSTRIDE)            // 9216: w_k = invLc_k mu_k, 8x32
#define C2OFF (WOFF + K*D)            // 9472: (c'_t - cmax)*log2(e), 36
#define CMAXOFF (C2OFF + NPAIR)       // 9508
#define PARTOFF 9600                  // per-block partial sums
#define STAGE_CNT (C2OFF + NPAIR)     // 9508 floats staged into LDS by main kernel

__host__ __device__ constexpr int gidx(int i, int j) {  // i<=j, i-major packed index
    return i * 8 + j - i * (i + 1) / 2;
}

// ---------------------------------------------------------------------------
// Setup: Cholesky of A_k = L_k L_k^T + I, invLc_k, w_k, pair constants c'_t.
// Single block, ~3-5 us; all heavy loops static-unrolled or row-parallel.
// ---------------------------------------------------------------------------
__global__ __launch_bounds__(256) void setup_kernel(
    const float* __restrict__ mu, const float* __restrict__ L,
    const float* __restrict__ weights, float* __restrict__ ws)
{
    __shared__ float sLc[K][D][D];   // A filled, then Cholesky in place (lower); upper never read
    __shared__ float sMu[K * D];
    __shared__ float sLogw[K];
    __shared__ float sCp[NPAIR];
    __shared__ float sCmax;

    const int tid = threadIdx.x;

    if (tid < K * D) sMu[tid] = mu[tid];

    // A[k][a][c] = sum_b L[k][a][b] L[k][c][b] + (a==c)
    for (int e = tid; e < K * D * D; e += 256) {
        const int k = e >> 10, a = (e >> 5) & 31, c = e & 31;
        const float* Lk = L + k * D * D;
        float s = (a == c) ? 1.0f : 0.0f;
        for (int b = 0; b < D; ++b) s = fmaf(Lk[a * D + b], Lk[c * D + b], s);
        sLc[k][a][c] = s;
    }
    __syncthreads();

    // Left-looking Cholesky, 32 row-threads per k
    {
        const int k = tid >> 5, i = tid & 31;
        for (int j = 0; j < D; ++j) {
            if (i == j) {
                float s = sLc[k][j][j];
                for (int b = 0; b < j; ++b) s -= sLc[k][j][b] * sLc[k][j][b];
                sLc[k][j][j] = sqrtf(s);
            }
            __syncthreads();
            if (i > j) {
                float s = sLc[k][i][j];
                for (int b = 0; b < j; ++b) s -= sLc[k][i][b] * sLc[k][j][b];
                sLc[k][i][j] = s / sLc[k][j][j];
            }
            __syncthreads();
        }
    }

    // w_k: solve Lc_k w = mu_k (forward substitution). logw = log_softmax(weights).
    if (tid < K) {
        const int k = tid;
        float wv[D];
        #pragma unroll
        for (int i = 0; i < D; ++i) {
            float s = sMu[k * D + i];
            #pragma unroll
            for (int b = 0; b < i; ++b) s -= sLc[k][i][b] * wv[b];
            wv[i] = s / sLc[k][i][i];
            ws[WOFF + k * D + i] = wv[i];
        }
    } else if (tid == K) {
        float m = -INFINITY;
        for (int i = 0; i < K; ++i) m = fmaxf(m, weights[i]);
        float s = 0.0f;
        for (int i = 0; i < K; ++i) s += expf(weights[i] - m);
        const float lse = m + logf(s);
        for (int i = 0; i < K; ++i) sLogw[i] = weights[i] - lse;
    }

    // invLc columns: thread (k, j) does predicated forward substitution for column j.
    // Rows i<j naturally give 0; diag gives 1/Lc[j][j]. Writes full padded matrix.
    {
        const int k = tid >> 5, j = tid & 31;
        float col[D];
        #pragma unroll
        for (int i = 0; i < D; ++i) {
            float s = (i == j) ? 1.0f : 0.0f;
            #pragma unroll
            for (int b = 0; b < i; ++b) {
                const float t = (b >= j) ? sLc[k][i][b] * col[b] : 0.0f;
                s -= t;
            }
            col[i] = s / sLc[k][i][i];
            ws[MOFF + k * D * MSTRIDE + i * MSTRIDE + j] = col[i];
        }
    }
    // zero pad columns 32..35
    for (int e = tid; e < K * D * (MSTRIDE - D); e += 256) {
        const int k = e / (D * (MSTRIDE - D));
        const int rem = e % (D * (MSTRIDE - D));
        const int i = rem / (MSTRIDE - D), p = rem % (MSTRIDE - D);
        ws[MOFF + k * D * MSTRIDE + i * MSTRIDE + D + p] = 0.0f;
    }
    __syncthreads();   // sLogw ready for pair phase

    // Pair constants c'_t for t in gidx order (i<=j).
    if (tid < NPAIR) {
        int tt = tid, i = 0;
        while (tt >= (K - i)) { tt -= (K - i); ++i; }
        const int j = i + tt;
        const float LOG2PI = 1.8378770664093453f;
        float sumlogS = 0.0f, logdetsig = 0.0f;
        #pragma unroll
        for (int r = 0; r < D; ++r) {
            const float di = sLc[i][r][r], dj = sLc[j][r][r];
            sumlogS += logf(di + dj);
            logdetsig -= logf(1.0f / di + 1.0f / dj);   // diag(M) = 1/di + 1/dj
        }
        // quad = -0.5 dmu^T inv(S) dmu, S = Lc_i + Lc_j (lower tri): forward solve
        float v[D];
        float quad_acc = 0.0f;
        #pragma unroll
        for (int r = 0; r < D; ++r) {
            const float d0 = sMu[i * D + r] - sMu[j * D + r];
            float s = d0;
            #pragma unroll
            for (int b = 0; b < r; ++b) s -= (sLc[i][r][b] + sLc[j][r][b]) * v[b];
            v[r] = s / (sLc[i][r][r] + sLc[j][r][r]);
            quad_acc = fmaf(d0, v[r], quad_acc);
        }
        const float quad = -0.5f * quad_acc;
        // c = z - 0.5*D*LOG2PI - 0.5*logdet(sigma) + logw_i + logw_j,
        // z = -0.5*(D*LOG2PI + sumlogS) + quad  =>  collapse:
        float c = quad - 0.5f * sumlogS - (float)D * LOG2PI - 0.5f * logdetsig
                  + sLogw[i] + sLogw[j];
        if (i < j) c += 0.6931471805599453f;   // multiplicity 2 for off-diagonal pairs
        sCp[tid] = c;
    }
    __syncthreads();
    if (tid == 0) {
        float m = -INFINITY;
        for (int t = 0; t < NPAIR; ++t) m = fmaxf(m, sCp[t]);
        sCmax = m;
        ws[CMAXOFF] = m;
    }
    __syncthreads();
    if (tid < NPAIR) {
        ws[C2OFF + tid] = (sCp[tid] - sCmax) * 1.4426950408889634f;  // pre-scaled by log2(e)
    }
}

// ---------------------------------------------------------------------------
// Main: 4 lanes per sample (roles = 8 interleaved rows each).
// y_k = invLc_k x - w_k; Gram G = Y Y^T via quad shuffles; then
// acc += exp2(c2_t - 0.5*log2e*(G_ii + G_jj + 2 G_ij)) over all 36 terms
// (all 4 lanes redundantly -> corrected by *0.25 at the end).
// ---------------------------------------------------------------------------
__global__ __launch_bounds__(256) void main_kernel(
    const float* __restrict__ X, const float* __restrict__ ws,
    float* __restrict__ partials, int nsamp)
{
    __shared__ __align__(16) float sAll[STAGE_CNT];   // invLc | w | c2  (~38 KB)
    __shared__ float sRed[4];
    const int tid = threadIdx.x;

    for (int i = tid; i < STAGE_CNT; i += 256) sAll[i] = ws[i];
    __syncthreads();

    const int role = tid & 3;
    const int n = blockIdx.x * 64 + (tid >> 2);
    float acc = 0.0f;

    if (n < nsamp) {
        // x in registers (float4 loads; 4-lane duplication served by L1)
        float x[D];
        const float4* Xv = (const float4*)X + n * 8;
        #pragma unroll
        for (int q = 0; q < 8; ++q) {
            const float4 t = Xv[q];
            x[4 * q + 0] = t.x; x[4 * q + 1] = t.y;
            x[4 * q + 2] = t.z; x[4 * q + 3] = t.w;
        }

        const float* sM = sAll;
        const float* sW = sAll + WOFF;
        float y[K][8];
        #pragma unroll
        for (int k = 0; k < K; ++k) {
            const float* Mk = sM + k * D * MSTRIDE;
            #pragma unroll
            for (int rh = 0; rh < 8; ++rh) {
                const int r = 4 * rh + role;
                float a = -sW[k * D + r];
                const float* Mr = Mk + r * MSTRIDE;
                // triangular: row r needs cols 0..r; float4 chunks 0..rh (uniform trip!)
                #pragma unroll
                for (int c4 = 0; c4 <= rh; ++c4) {
                    const float4 m4 = *(const float4*)(Mr + 4 * c4);
                    a = fmaf(m4.x, x[4 * c4 + 0], a);
                    a = fmaf(m4.y, x[4 * c4 + 1], a);
                    a = fmaf(m4.z, x[4 * c4 + 2], a);
                    a = fmaf(m4.w, x[4 * c4 + 3], a);
                }
                y[k][rh] = a;
            }
        }

        // Gram partials over this lane's 8 rows, then combine across the quad
        float g[NPAIR];
        #pragma unroll
        for (int i = 0; i < K; ++i)
            #pragma unroll
            for (int j = i; j < K; ++j) {
                float a = 0.0f;
                #pragma unroll
                for (int rh = 0; rh < 8; ++rh) a = fmaf(y[i][rh], y[j][rh], a);
                g[gidx(i, j)] = a;
            }
        #pragma unroll
        for (int t = 0; t < NPAIR; ++t) {
            g[t] += __shfl_xor(g[t], 1, 64);
            g[t] += __shfl_xor(g[t], 2, 64);
        }

        // 36-term sum, fixed-max (v <= 0 by construction: c2 <= 0, q >= 0)
        const float* c2 = sAll + C2OFF;
        const float NH = -0.72134752044448170f;   // -0.5 * log2(e)
        #pragma unroll
        for (int i = 0; i < K; ++i)
            #pragma unroll
            for (int j = i; j < K; ++j) {
                const float q = fmaf(2.0f, g[gidx(i, j)], g[gidx(i, i)] + g[gidx(j, j)]);
                acc += exp2f(fmaf(NH, q, c2[gidx(i, j)]));
            }
    }

    // block reduction (every lane counted; 4x sample redundancy fixed in finish)
    #pragma unroll
    for (int m = 1; m < 64; m <<= 1) acc += __shfl_xor(acc, m, 64);
    if ((tid & 63) == 0) sRed[tid >> 6] = acc;
    __syncthreads();
    if (tid == 0) partials[blockIdx.x] = sRed[0] + sRed[1] + sRed[2] + sRed[3];
}

__global__ __launch_bounds__(256) void finish_kernel(
    const float* __restrict__ partials, const float* __restrict__ ws,
    float* __restrict__ out, int nblk)
{
    __shared__ float sRed[4];
    const int tid = threadIdx.x;
    float acc = 0.0f;
    for (int i = tid; i < nblk; i += 256) acc += partials[i];
    #pragma unroll
    for (int m = 1; m < 64; m <<= 1) acc += __shfl_xor(acc, m, 64);
    if ((tid & 63) == 0) sRed[tid >> 6] = acc;
    __syncthreads();
    if (tid == 0) {
        const float total = sRed[0] + sRed[1] + sRed[2] + sRed[3];
        out[0] = ws[CMAXOFF] + logf(total * 0.25f);   // undo 4x lane redundancy
    }
}

extern "C" void kernel_launch(void* const* d_in, const int* in_sizes, int n_in,
                              void* d_out, int out_size, void* d_ws, size_t ws_size,
                              hipStream_t stream) {
    const float* X = (const float*)d_in[0];
    const float* mu = (const float*)d_in[1];
    const float* L = (const float*)d_in[2];
    const float* w = (const float*)d_in[3];
    float* wsf = (float*)d_ws;
    float* out = (float*)d_out;

    const int nsamp = in_sizes[0] / D;
    const int nblk = (nsamp + 63) / 64;

    setup_kernel<<<1, 256, 0, stream>>>(mu, L, w, wsf);
    main_kernel<<<nblk, 256, 0, stream>>>(X, wsf, wsf + PARTOFF, nsamp);
    finish_kernel<<<1, 256, 0, stream>>>(wsf + PARTOFF, wsf, out, nblk);
}